// Round 1
// baseline (1754.782 us; speedup 1.0000x reference)
//
#include <hip/hip_runtime.h>
#include <stdint.h>

#define N_NODES 4096
#define F_DIM   64
#define LRELU_ALPHA 0.2f

typedef _Float16 f16;
typedef __attribute__((ext_vector_type(8))) _Float16 half8;  // MFMA f16 A/B frag (4 VGPRs)
typedef __attribute__((ext_vector_type(4))) float f32x4;     // MFMA C/D frag

// ---------------------------------------------------------------------------
// Kernel 1: PREP ONLY (pack role moved into gat_attn). 1024 blocks x 256.
// Wh = h@W; ei=Wh·a1, ej=Wh·a2; whB in MFMA B-fragment order:
//   whB[((b*128+jc)*4+fc)*512 + (q*16+m)*8 + x] = Wh[j=jc*32+q*8+x][f=fc*16+m]
// blockmax[pid] = max ej over the block's 16 rows.
// ---------------------------------------------------------------------------
__global__ __launch_bounds__(256) void gat_prep(
    const float* __restrict__ h, const float* __restrict__ W,
    const float* __restrict__ a,
    float* __restrict__ ei, float* __restrict__ ej,
    f16* __restrict__ whB, float* __restrict__ blockmax)
{
  __shared__ float sh_h[4][F_DIM];
  __shared__ f16 tile[F_DIM][16];   // [f][loc]
  __shared__ float wmax[4];
  const int t = threadIdx.x, w = t >> 6, lane = t & 63;
  const int pid = blockIdx.x;
  const int n0 = pid * 16;              // global row base (0..16383)
  const int b  = n0 >> 12;
  const int nl0 = n0 & (N_NODES - 1);   // row base within batch

  float wcol[F_DIM];
#pragma unroll
  for (int k = 0; k < F_DIM; ++k) wcol[k] = W[k * F_DIM + lane];
  const float a1 = a[lane], a2 = a[F_DIM + lane];

  float runmax = -3e38f;
  for (int r = 0; r < 4; ++r) {
    const int loc = w * 4 + r;
    const int n = n0 + loc;
    const float hv = h[(size_t)n * F_DIM + lane];
    sh_h[w][lane] = hv;                       // same-wave LDS write->read
    float wh = 0.f;
#pragma unroll
    for (int k = 0; k < F_DIM; k += 4) {
      const float4 hb = *(const float4*)(&sh_h[w][k]);
      wh = fmaf(hb.x, wcol[k + 0], wh);
      wh = fmaf(hb.y, wcol[k + 1], wh);
      wh = fmaf(hb.z, wcol[k + 2], wh);
      wh = fmaf(hb.w, wcol[k + 3], wh);
    }
    float s1 = wh * a1, s2 = wh * a2;
#pragma unroll
    for (int off = 32; off; off >>= 1) {
      s1 += __shfl_xor(s1, off);
      s2 += __shfl_xor(s2, off);
    }
    if (lane == 0) { ei[n] = s1; ej[n] = s2; }
    runmax = fmaxf(runmax, s2);               // s2 identical on all lanes
    tile[lane][loc] = (f16)wh;                // f = lane
  }
  if (lane == 0) wmax[w] = runmax;
  __syncthreads();

  // B-fragment-order store (coalesced 8-B): jc/q0 fixed per block.
  {
    const int jc = nl0 >> 5;
    const int q0 = (nl0 >> 3) & 3;            // in {0, 2}
    const int fc = t >> 6;
    const int r6 = t & 63;
    const int qp = r6 >> 5;                   // q' in {0,1}
    const int m  = (r6 >> 1) & 15;
    const int xh = (t & 1) * 4;
    const int loc = qp * 8 + xh;              // source loc (+0..3)
    f16* dst = whB + (((size_t)(b * 128 + jc)) * 4 + fc) * 512
                   + ((q0 + qp) * 16 + m) * 8 + xh;
    *(uint2*)dst = *(const uint2*)(&tile[fc * 16 + m][loc]);
  }
  if (t == 0)
    blockmax[pid] =
        fmaxf(fmaxf(wmax[0], wmax[1]), fmaxf(wmax[2], wmax[3]));
}

// ---------------------------------------------------------------------------
// Kernel 2: FUSED pack + attention + PV (f16 MFMA) + ELU. Block = 32 rows,
// 512 thr = 8 waves, grid 512 = 2 blocks/CU (LDS 74.75 KB caps at 2).
// adj is now streamed HERE, in 4 chunks of 1024 j, ballot-packed into a
// double-buffered LDS bits buffer (bits never touch HBM; 16 MB round-trip
// gone). Chunk c+1's 16-deep load groups are issued between the ji
// iterations of chunk c -> the 268 MB adj stream hides under exp/MFMA.
// Wave w packs local rows [4w,4w+4); in attn it sweeps j-subwindow
// [c*1024 + w*128, +128) for BOTH 16-row i-tiles per chunk.
// sh_bits row stride = 36 dwords (144 B): pad keeps ds_read_b128 2-way max.
// Range control per tile: bnd = leaky(ei + maxej_batch) >= row max;
// arg = max(ej+c1, fma(0.2,ej,c2)) <= 0 -> p in (0,1], f16-safe.
// A-frag: A[m=lane&15][k=quad*8+x]; B-frag: B[k=quad*8+x][n=m];
// C/D: row=quad*4+reg, col=lane&15 (HW-verified m89/m91).
// ---------------------------------------------------------------------------
__global__ __launch_bounds__(512, 4) void gat_attn(
    const int* __restrict__ adj, const float* __restrict__ ei,
    const float* __restrict__ ej, const f16* __restrict__ whB,
    const float* __restrict__ blockmax, float* __restrict__ out)
{
  __shared__ float num_lds[8][32][F_DIM];   // 64 KB
  __shared__ float den_lds[8][32];          // 1 KB
  __shared__ uint32_t sh_bits[2][32][36];   // 9 KB, padded row stride

  const int t = threadIdx.x, w = t >> 6, lane = t & 63;
  const int quad = lane >> 4, m = lane & 15;
  const int b  = blockIdx.x >> 7;            // 128 32-row chunks per batch
  const int i0 = (blockIdx.x & 127) * 32;
  const int rowg0 = b * N_NODES + i0 + m;        // tile 0 row
  const int rowg1 = rowg0 + 16;                  // tile 1 row

  // per-batch max(ej): reduce 256 per-block maxima (L2-hot)
  float maxej;
  {
    const float4 v = *(const float4*)(blockmax + b * 256 + lane * 4);
    maxej = fmaxf(fmaxf(v.x, v.y), fmaxf(v.z, v.w));
#pragma unroll
    for (int off = 32; off; off >>= 1)
      maxej = fmaxf(maxej, __shfl_xor(maxej, off));
  }

  const float ei0 = ei[rowg0], ei1 = ei[rowg1];
  float bnd0 = ei0 + maxej;
  bnd0 = fmaxf(bnd0, LRELU_ALPHA * bnd0);
  float bnd1 = ei1 + maxej;
  bnd1 = fmaxf(bnd1, LRELU_ALPHA * bnd1);
  const float c10 = ei0 - bnd0, c20 = LRELU_ALPHA * ei0 - bnd0;
  const float c11 = ei1 - bnd1, c21 = LRELU_ALPHA * ei1 - bnd1;

  const float* ejb = ej + b * N_NODES;
  const int*  adjw = adj + ((size_t)(b * N_NODES + i0 + w * 4)) * N_NODES;
  const f16*  whw  = whB + ((size_t)(b * 128)) * 2048 + lane * 8;

  f32x4 acc0[4] = {{0.f,0.f,0.f,0.f},{0.f,0.f,0.f,0.f},
                   {0.f,0.f,0.f,0.f},{0.f,0.f,0.f,0.f}};
  f32x4 acc1[4] = {{0.f,0.f,0.f,0.f},{0.f,0.f,0.f,0.f},
                   {0.f,0.f,0.f,0.f},{0.f,0.f,0.f,0.f}};
  float den0 = 0.f, den1 = 0.f;

  // ---- prologue: pack chunk 0 into buffer 0 (16 loads in flight/group) ----
  {
#pragma unroll
    for (int g = 0; g < 4; ++g) {
      int v[16];
#pragma unroll
      for (int s = 0; s < 16; ++s)
        v[s] = adjw[(size_t)g * N_NODES + s * 64 + lane];
#pragma unroll
      for (int s = 0; s < 16; ++s) {
        const unsigned long long mm = __ballot(v[s] > 0);
        if (lane == 0)
          *(uint64_t*)&sh_bits[0][w * 4 + g][2 * s] = mm;
      }
    }
  }
  __syncthreads();

  for (int c = 0; c < 4; ++c) {
    const int cur = c & 1, nxt = cur ^ 1;
    const int* apn = adjw + (c + 1) * 1024;   // next chunk (unused at c==3)

    // this wave's 4 bit-dwords per tile row for the chunk (2-way max conflict)
    const uint4 dq0 = *(const uint4*)&sh_bits[cur][m][w * 4];
    const uint4 dq1 = *(const uint4*)&sh_bits[cur][m + 16][w * 4];
    const uint32_t dws0[4] = {dq0.x, dq0.y, dq0.z, dq0.w};
    const uint32_t dws1[4] = {dq1.x, dq1.y, dq1.z, dq1.w};

#pragma unroll
    for (int g = 0; g < 4; ++g) {
      // ---- stage next chunk, row-group g: issue loads BEFORE compute ----
      int v[16];
      if (c < 3) {
#pragma unroll
        for (int s = 0; s < 16; ++s)
          v[s] = apn[(size_t)g * N_NODES + s * 64 + lane];
      }

      // ---- attn ji = g on current chunk ----
      const int jcg = c * 32 + w * 4 + g;       // global 32-j chunk index
      const int jk  = jcg * 32 + quad * 8;
      const uint32_t dw0 = dws0[g], dw1 = dws1[g];

      float ejA[8];
      *(float4*)(&ejA[0]) = *(const float4*)(ejb + jk);
      *(float4*)(&ejA[4]) = *(const float4*)(ejb + jk + 4);

      const f16* wjc = whw + (size_t)jcg * 2048;
      half8 bf[4];
#pragma unroll
      for (int fc = 0; fc < 4; ++fc)
        bf[fc] = *(const half8*)(wjc + fc * 512);

      half8 pa0, pa1;
#pragma unroll
      for (int x = 0; x < 8; ++x) {
        const float e = ejA[x];
        const float g0 = fmaxf(e + c10, fmaf(LRELU_ALPHA, e, c20));
        const float g1 = fmaxf(e + c11, fmaf(LRELU_ALPHA, e, c21));
        const float p0 = ((dw0 >> (quad * 8 + x)) & 1u) ? __expf(g0) : 0.f;
        const float p1 = ((dw1 >> (quad * 8 + x)) & 1u) ? __expf(g1) : 0.f;
        pa0[x] = (f16)p0;
        pa1[x] = (f16)p1;
        den0 += (float)pa0[x];
        den1 += (float)pa1[x];
      }

#pragma unroll
      for (int fc = 0; fc < 4; ++fc) {
        acc0[fc] = __builtin_amdgcn_mfma_f32_16x16x32_f16(pa0, bf[fc], acc0[fc], 0, 0, 0);
        acc1[fc] = __builtin_amdgcn_mfma_f32_16x16x32_f16(pa1, bf[fc], acc1[fc], 0, 0, 0);
      }

      // ---- finish staging row-group g into the other buffer ----
      if (c < 3) {
#pragma unroll
        for (int s = 0; s < 16; ++s) {
          const unsigned long long mm = __ballot(v[s] > 0);
          if (lane == 0)
            *(uint64_t*)&sh_bits[nxt][w * 4 + g][2 * s] = mm;
        }
      }
    }
    __syncthreads();   // buf[nxt] complete; buf[cur] free for c+2's writes
  }

  // den: lanes sharing a row (same lane&15) live 16 apart
  den0 += __shfl_xor(den0, 16);
  den0 += __shfl_xor(den0, 32);
  den1 += __shfl_xor(den1, 16);
  den1 += __shfl_xor(den1, 32);
  if (lane < 16) {
    den_lds[w][lane] = den0;
    den_lds[w][lane + 16] = den1;
  }

#pragma unroll
  for (int fc = 0; fc < 4; ++fc)
#pragma unroll
    for (int rg = 0; rg < 4; ++rg) {
      num_lds[w][quad * 4 + rg][fc * 16 + m] = acc0[fc][rg];
      num_lds[w][16 + quad * 4 + rg][fc * 16 + m] = acc1[fc][rg];
    }
  __syncthreads();

  // merge 8 wave-partials, divide, ELU, coalesced store (2048 outs, 512 thr)
#pragma unroll
  for (int k = 0; k < 4; ++k) {
    const int idx = k * 512 + t;
    const int il = idx >> 6, f = idx & 63;
    float num = 0.f, d = 0.f;
#pragma unroll
    for (int ww = 0; ww < 8; ++ww) {
      num += num_lds[ww][il][f];
      d   += den_lds[ww][il];
    }
    float v = (d > 0.f) ? (num / d) : 0.f;
    v = (v > 0.f) ? v : expm1f(v);
    out[((size_t)(b * N_NODES + i0 + il)) * F_DIM + f] = v;
  }
}

extern "C" void kernel_launch(void* const* d_in, const int* in_sizes, int n_in,
                              void* d_out, int out_size, void* d_ws, size_t ws_size,
                              hipStream_t stream) {
  const float* h   = (const float*)d_in[0];
  const int*   adj = (const int*)d_in[1];
  const float* W   = (const float*)d_in[2];
  const float* a   = (const float*)d_in[3];
  float* out = (float*)d_out;

  char* ws = (char*)d_ws;
  // Workspace (~2.23 MB, bits buffer eliminated):
  // [0,       +64 KB)  ei
  // [65536,   +64 KB)  ej
  // [131072,  +4 KB)   blockmax (1024 floats)
  // [135168,  +2 MB)   whB (B-fragment-order Wh, 2M f16 exactly)
  float*    ei       = (float*)ws;
  float*    ej       = (float*)(ws + 65536);
  float*    blockmax = (float*)(ws + 131072);
  f16*      whB      = (f16*)(ws + 135168);

  hipLaunchKernelGGL(gat_prep, dim3(1024), dim3(256), 0, stream,
                     h, W, a, ei, ej, whB, blockmax);
  hipLaunchKernelGGL(gat_attn, dim3(512), dim3(512), 0, stream,
                     adj, ei, ej, whB, blockmax, out);
}

// Round 2
// 392.550 us; speedup vs baseline: 4.4702x; 4.4702x over previous
//
#include <hip/hip_runtime.h>
#include <stdint.h>

#define N_NODES 4096
#define F_DIM   64
#define LRELU_ALPHA 0.2f

typedef _Float16 f16;
typedef __attribute__((ext_vector_type(8))) _Float16 half8;  // MFMA f16 A/B frag (4 VGPRs)
typedef __attribute__((ext_vector_type(4))) float f32x4;     // MFMA C/D frag

// ---------------------------------------------------------------------------
// Kernel 0+1 FUSED, roles INTERLEAVED 1:5. blockIdx%5==0 -> prep (1024 of
// 5120), else pack (4096 blocks x 4 rows). prep's VALU/LDS work rides under
// pack's HBM stream. vs round-0: pack blocks carry 4 rows each (one row per
// wave, 4 batches of 16 ballot'd dword loads) -> 17408 -> 5120 dispatches,
// same coalescing (256 B/wave-instr), batch loop unroll(1) caps in-flight
// loads at 16 (spill discipline -- round-1 lesson).
// pack: bits[row*128 + d] bit (j&31) = adj[row][j] > 0.
// prep: Wh = h@W; ei=Wh·a1, ej=Wh·a2; whB in MFMA B-fragment order:
//   whB[((b*128+jc)*4+fc)*512 + (q*16+m)*8 + x] = Wh[j=jc*32+q*8+x][f=fc*16+m]
//   blockmax[pid] = max ej over the prep block's 16 rows.
// ---------------------------------------------------------------------------
__global__ __launch_bounds__(256) void gat_pp(
    const float* __restrict__ h, const float* __restrict__ W,
    const float* __restrict__ a, const int* __restrict__ adj,
    float* __restrict__ ei, float* __restrict__ ej,
    f16* __restrict__ whB, float* __restrict__ blockmax,
    uint32_t* __restrict__ bits)
{
  __shared__ float sh_h[4][F_DIM];
  __shared__ f16 tile[F_DIM][16];   // [f][loc]
  __shared__ float wmax[4];
  const int t = threadIdx.x, w = t >> 6, lane = t & 63;
  const int bid = blockIdx.x;
  const int pid = bid / 5;

  if (bid % 5 != 0) {
    // ---------------- pack role: 4 rows/block, 1 row/wave ----------------
    const int pk = bid - 1 - pid;                 // 0..4095
    const int row = pk * 4 + w;                   // this wave's adj row
    const int* rowp = adj + (size_t)row * N_NODES + lane;
    uint64_t* dst = (uint64_t*)(bits + (size_t)row * 128);

#pragma unroll 1
    for (int bch = 0; bch < 4; ++bch) {           // 4 batches of 1024 j
      int v[16];
#pragma unroll
      for (int s = 0; s < 16; ++s)
        v[s] = rowp[(bch * 16 + s) * 64];         // 16 loads in flight, 256B/instr
#pragma unroll
      for (int s = 0; s < 16; ++s) {
        const unsigned long long m = __ballot(v[s] > 0);
        if (lane == 0) dst[bch * 16 + s] = m;
      }
    }
    return;
  }

  // ---------------- prep role ----------------
  const int n0 = pid * 16;              // global row base (0..16383)
  const int b  = n0 >> 12;
  const int nl0 = n0 & (N_NODES - 1);   // row base within batch

  float wcol[F_DIM];
#pragma unroll
  for (int k = 0; k < F_DIM; ++k) wcol[k] = W[k * F_DIM + lane];
  const float a1 = a[lane], a2 = a[F_DIM + lane];

  float runmax = -3e38f;
  for (int r = 0; r < 4; ++r) {
    const int loc = w * 4 + r;
    const int n = n0 + loc;
    const float hv = h[(size_t)n * F_DIM + lane];
    sh_h[w][lane] = hv;                       // same-wave LDS write->read
    float wh = 0.f;
#pragma unroll
    for (int k = 0; k < F_DIM; k += 4) {
      const float4 hb = *(const float4*)(&sh_h[w][k]);
      wh = fmaf(hb.x, wcol[k + 0], wh);
      wh = fmaf(hb.y, wcol[k + 1], wh);
      wh = fmaf(hb.z, wcol[k + 2], wh);
      wh = fmaf(hb.w, wcol[k + 3], wh);
    }
    float s1 = wh * a1, s2 = wh * a2;
#pragma unroll
    for (int off = 32; off; off >>= 1) {
      s1 += __shfl_xor(s1, off);
      s2 += __shfl_xor(s2, off);
    }
    if (lane == 0) { ei[n] = s1; ej[n] = s2; }
    runmax = fmaxf(runmax, s2);               // s2 identical on all lanes
    tile[lane][loc] = (f16)wh;                // f = lane
  }
  if (lane == 0) wmax[w] = runmax;
  __syncthreads();

  // B-fragment-order store (coalesced 8-B): jc/q0 fixed per block.
  {
    const int jc = nl0 >> 5;
    const int q0 = (nl0 >> 3) & 3;            // in {0, 2}
    const int fc = t >> 6;
    const int r6 = t & 63;
    const int qp = r6 >> 5;                   // q' in {0,1}
    const int m  = (r6 >> 1) & 15;
    const int xh = (t & 1) * 4;
    const int loc = qp * 8 + xh;              // source loc (+0..3)
    f16* dst = whB + (((size_t)(b * 128 + jc)) * 4 + fc) * 512
                   + ((q0 + qp) * 16 + m) * 8 + xh;
    *(uint2*)dst = *(const uint2*)(&tile[fc * 16 + m][loc]);
  }
  if (t == 0)
    blockmax[pid] =
        fmaxf(fmaxf(wmax[0], wmax[1]), fmaxf(wmax[2], wmax[3]));
}

// ---------------------------------------------------------------------------
// Kernel 2: attention + PV (f16 MFMA) + ELU. Block = 32 rows (two 16-row
// i-tiles), 512 thr = 8 waves; wave w sweeps j in [w*512,(w+1)*512).
// SPILL FIX vs round-0: the jo/ji nested loop (unroll 4) let the compiler
// hoist 4 iterations' bf[4]+ejA loads (~96 VGPRs) over a ~100-VGPR base ->
// scratch. Now: flat jc loop, #pragma unroll 1, ONE iteration's loads in
// flight (~26 regs transient); bit-dwords read per-iter from L2-hot bits
// (no uint4 staging arrays). den accumulated in f32 (drops 16 f16->f32
// back-cvts/iter, halves the serial fadd chain).
// Range control per tile: bnd = leaky(ei + maxej_batch) >= row max (leaky
// monotone); arg = max(ej+c1, fma(0.2,ej,c2)) <= 0 -> p in (0,1], f16-safe;
// shift cancels in num/den.
// A-frag: A[m=lane&15][k=quad*8+x]; B-frag: B[k=quad*8+x][n=m];
// C/D: row=quad*4+reg, col=lane&15 (HW-verified m89/m91).
// ---------------------------------------------------------------------------
__global__ __launch_bounds__(512, 4) void gat_attn(
    const uint32_t* __restrict__ bits, const float* __restrict__ ei,
    const float* __restrict__ ej, const f16* __restrict__ whB,
    const float* __restrict__ blockmax, float* __restrict__ out)
{
  __shared__ float num_lds[8][32][F_DIM];   // 64 KB
  __shared__ float den_lds[8][32];          // 1 KB

  const int t = threadIdx.x, w = t >> 6, lane = t & 63;
  const int quad = lane >> 4, m = lane & 15;
  const int kq = quad * 8;
  const int b  = blockIdx.x >> 7;            // 128 32-row chunks per batch
  const int i0 = (blockIdx.x & 127) * 32;
  const int rowg0 = b * N_NODES + i0 + m;        // tile 0 row (this lane)
  const int rowg1 = rowg0 + 16;                  // tile 1 row

  // per-batch max(ej): reduce 256 per-block maxima (L2-hot)
  float maxej;
  {
    const float4 v = *(const float4*)(blockmax + b * 256 + lane * 4);
    maxej = fmaxf(fmaxf(v.x, v.y), fmaxf(v.z, v.w));
#pragma unroll
    for (int off = 32; off; off >>= 1)
      maxej = fmaxf(maxej, __shfl_xor(maxej, off));
  }

  const float ei0 = ei[rowg0], ei1 = ei[rowg1];
  float bnd0 = ei0 + maxej;
  bnd0 = fmaxf(bnd0, LRELU_ALPHA * bnd0);
  float bnd1 = ei1 + maxej;
  bnd1 = fmaxf(bnd1, LRELU_ALPHA * bnd1);
  const float c10 = ei0 - bnd0, c20 = LRELU_ALPHA * ei0 - bnd0;
  const float c11 = ei1 - bnd1, c21 = LRELU_ALPHA * ei1 - bnd1;

  const float* ejb = ej + b * N_NODES + w * 512;       // this wave's j window
  const uint32_t* bitrow0 = bits + (size_t)rowg0 * 128 + w * 16;
  const uint32_t* bitrow1 = bits + (size_t)rowg1 * 128 + w * 16;
  const f16* whw = whB + ((size_t)(b * 128 + w * 16)) * 2048 + lane * 8;

  f32x4 acc0[4] = {{0.f,0.f,0.f,0.f},{0.f,0.f,0.f,0.f},
                   {0.f,0.f,0.f,0.f},{0.f,0.f,0.f,0.f}};
  f32x4 acc1[4] = {{0.f,0.f,0.f,0.f},{0.f,0.f,0.f,0.f},
                   {0.f,0.f,0.f,0.f},{0.f,0.f,0.f,0.f}};
  float dA0 = 0.f, dB0 = 0.f, dA1 = 0.f, dB1 = 0.f;

#pragma unroll 1
  for (int jc = 0; jc < 16; ++jc) {
    const uint32_t dw0 = bitrow0[jc];       // bits for row m,   dword jc
    const uint32_t dw1 = bitrow1[jc];       // bits for row m+16

    float ejA[8];
    *(float4*)(&ejA[0]) = *(const float4*)(ejb + jc * 32 + kq);
    *(float4*)(&ejA[4]) = *(const float4*)(ejb + jc * 32 + kq + 4);

    const f16* wjc = whw + (size_t)jc * 2048;
    half8 bf[4];
#pragma unroll
    for (int fc = 0; fc < 4; ++fc)
      bf[fc] = *(const half8*)(wjc + fc * 512);

    half8 pa0, pa1;
#pragma unroll
    for (int x = 0; x < 8; ++x) {
      const float e = ejA[x];
      const float g0 = fmaxf(e + c10, fmaf(LRELU_ALPHA, e, c20));
      const float g1 = fmaxf(e + c11, fmaf(LRELU_ALPHA, e, c21));
      const float p0 = ((dw0 >> (kq + x)) & 1u) ? __expf(g0) : 0.f;
      const float p1 = ((dw1 >> (kq + x)) & 1u) ? __expf(g1) : 0.f;
      pa0[x] = (f16)p0;
      pa1[x] = (f16)p1;
      if (x & 1) { dB0 += p0; dB1 += p1; }   // two chains: half the depth
      else       { dA0 += p0; dA1 += p1; }
    }

#pragma unroll
    for (int fc = 0; fc < 4; ++fc) {
      acc0[fc] = __builtin_amdgcn_mfma_f32_16x16x32_f16(pa0, bf[fc], acc0[fc], 0, 0, 0);
      acc1[fc] = __builtin_amdgcn_mfma_f32_16x16x32_f16(pa1, bf[fc], acc1[fc], 0, 0, 0);
    }
  }

  float den0 = dA0 + dB0, den1 = dA1 + dB1;
  // den: lanes sharing a row (same lane&15) live 16 apart
  den0 += __shfl_xor(den0, 16);
  den0 += __shfl_xor(den0, 32);
  den1 += __shfl_xor(den1, 16);
  den1 += __shfl_xor(den1, 32);
  if (lane < 16) {
    den_lds[w][lane] = den0;
    den_lds[w][lane + 16] = den1;
  }

#pragma unroll
  for (int fc = 0; fc < 4; ++fc)
#pragma unroll
    for (int rg = 0; rg < 4; ++rg) {
      num_lds[w][quad * 4 + rg][fc * 16 + m] = acc0[fc][rg];
      num_lds[w][16 + quad * 4 + rg][fc * 16 + m] = acc1[fc][rg];
    }
  __syncthreads();

  // merge 8 wave-partials, divide, ELU, coalesced store (2048 outs, 512 thr)
#pragma unroll
  for (int k = 0; k < 4; ++k) {
    const int idx = k * 512 + t;
    const int il = idx >> 6, f = idx & 63;
    float num = 0.f, d = 0.f;
#pragma unroll
    for (int ww = 0; ww < 8; ++ww) {
      num += num_lds[ww][il][f];
      d   += den_lds[ww][il];
    }
    float v = (d > 0.f) ? (num / d) : 0.f;
    v = (v > 0.f) ? v : expm1f(v);
    out[((size_t)(b * N_NODES + i0 + il)) * F_DIM + f] = v;
  }
}

extern "C" void kernel_launch(void* const* d_in, const int* in_sizes, int n_in,
                              void* d_out, int out_size, void* d_ws, size_t ws_size,
                              hipStream_t stream) {
  const float* h   = (const float*)d_in[0];
  const int*   adj = (const int*)d_in[1];
  const float* W   = (const float*)d_in[2];
  const float* a   = (const float*)d_in[3];
  float* out = (float*)d_out;

  char* ws = (char*)d_ws;
  // Workspace (~10.2 MB):
  // [0,       +64 KB)  ei
  // [65536,   +64 KB)  ej
  // [131072,  +4 KB)   blockmax (1024 floats, fully written by prep role)
  // [135168,  +2 MB)   whB (B-fragment-order Wh, 2M f16 exactly)
  // [2232320, +8 MB)   bits (2M dwords, fully written by pack role)
  float*    ei       = (float*)ws;
  float*    ej       = (float*)(ws + 65536);
  float*    blockmax = (float*)(ws + 131072);
  f16*      whB      = (f16*)(ws + 135168);
  uint32_t* bits     = (uint32_t*)(ws + 2232320);

  hipLaunchKernelGGL(gat_pp, dim3(5120), dim3(256), 0, stream,
                     h, W, a, adj, ei, ej, whB, blockmax, bits);
  hipLaunchKernelGGL(gat_attn, dim3(512), dim3(512), 0, stream,
                     bits, ei, ej, whB, blockmax, out);
}